// Round 1
// baseline (911.344 us; speedup 1.0000x reference)
//
#include <hip/hip_runtime.h>
#include <hip/hip_bf16.h>
#include <math.h>

#define NCLS 21
#define HW41 41
#define WH 1681          // 41*41
#define BS 4
#define CIN 2048
#define CMID 1024
#define KPOS 18432       // 2048*9

// ---------------- ws layout (floats) ----------------
// xup     : [4][2048][41][41]            13,774,848
// w2      : [2048][24][12]  (c pad 24, tap pad 12)  589,824
// g       : [4][21][1681]                  141,204
// Kc      : [32]                                32
// wcum    : [4][4][21][1681]               564,816
#define WS_XUP   0L
#define WS_W2    13774848L
#define WS_G     (WS_W2 + 589824L)
#define WS_KC    (WS_G + 141204L)
#define WS_WCUM  (WS_KC + 32L)
#define WS_TOTAL (WS_WCUM + 564816L)

// ---------------- kernels ----------------

__global__ void k_upsample(const float* __restrict__ x, float* __restrict__ xup, int total) {
    int idx = blockIdx.x * blockDim.x + threadIdx.x;
    if (idx >= total) return;
    int xx = idx % 41;
    int t = idx / 41;
    int yy = t % 41;
    int bi = t / 41;                       // b*2048 + i
    const float S = 33.0f / 41.0f;
    float sy = (yy + 0.5f) * S - 0.5f;
    float sx = (xx + 0.5f) * S - 0.5f;
    float fy = floorf(sy), fx = floorf(sx);
    int y0 = (int)fy, x0 = (int)fx;
    float wy = sy - fy, wx = sx - fx;
    int y0c = min(max(y0, 0), 32), y1c = min(max(y0 + 1, 0), 32);
    int x0c = min(max(x0, 0), 32), x1c = min(max(x0 + 1, 0), 32);
    const float* base = x + (long)bi * 1089;
    float v00 = base[y0c * 33 + x0c], v01 = base[y0c * 33 + x1c];
    float v10 = base[y1c * 33 + x0c], v11 = base[y1c * 33 + x1c];
    float v0 = v00 + wx * (v01 - v00);
    float v1 = v10 + wx * (v11 - v10);
    xup[idx] = v0 + wy * (v1 - v0);
}

// W2[c, pos] = sum_d cls_w[c,d] * conv_w[d,pos]; layout w2[i][c(24)][tap(12)]
// grid (288, 2) x 256 threads; d-split 2 with atomicAdd (w2 pre-zeroed)
__global__ void k_merge(const float* __restrict__ convw, const float* __restrict__ clsw,
                        float* __restrict__ w2) {
    int pos = blockIdx.x * 64 + (threadIdx.x & 63);
    int cg  = threadIdx.x >> 6;            // 0..3
    int d0  = blockIdx.y * 512;
    float acc[6] = {0, 0, 0, 0, 0, 0};
    for (int d = d0; d < d0 + 512; d += 4) {
        float c0 = convw[(long)(d + 0) * KPOS + pos];
        float c1 = convw[(long)(d + 1) * KPOS + pos];
        float c2 = convw[(long)(d + 2) * KPOS + pos];
        float c3 = convw[(long)(d + 3) * KPOS + pos];
#pragma unroll
        for (int j = 0; j < 6; ++j) {
            int c = cg + 4 * j;
            if (c < NCLS) {
                const float4 w = *(const float4*)&clsw[c * 1024 + d];
                acc[j] += w.x * c0 + w.y * c1 + w.z * c2 + w.w * c3;
            }
        }
    }
    int i = pos / 9, tap = pos - i * 9;
#pragma unroll
    for (int j = 0; j < 6; ++j) {
        int c = cg + 4 * j;
        if (c < NCLS) atomicAdd(&w2[((long)i * 24 + c) * 12 + tap], acc[j]);
    }
}

// Kc[c] = sum_d cls_w[c,d]*conv_b[d] + cls_b[c] ; grid 21 x 256
__global__ void k_const(const float* __restrict__ clsw, const float* __restrict__ convb,
                        const float* __restrict__ clsb, float* __restrict__ Kc) {
    __shared__ float red[256];
    int c = blockIdx.x;
    float s = 0.f;
    for (int d = threadIdx.x; d < 1024; d += 256) s += clsw[c * 1024 + d] * convb[d];
    red[threadIdx.x] = s; __syncthreads();
    for (int o = 128; o > 0; o >>= 1) {
        if (threadIdx.x < o) red[threadIdx.x] += red[threadIdx.x + o];
        __syncthreads();
    }
    if (threadIdx.x == 0) Kc[c] = red[0] + clsb[c];
}

// dilated 3x3 conv (dil=6,pad=6) with merged 21-class weights.
// grid (27, 4, 8) x 256 : m-tile 64 (lanes), 4 class-groups (waves), 8 channel splits (256 ch each)
// accumulates into g[b][c][m] via atomicAdd (g pre-zeroed)
__global__ void k_conv(const float* __restrict__ xup, const float* __restrict__ w2,
                       float* __restrict__ g) {
    int lane = threadIdx.x & 63;
    int cg   = threadIdx.x >> 6;
    int m    = blockIdx.x * 64 + lane;
    int b    = blockIdx.y;
    int i0   = blockIdx.z * 256;
    bool valid = m < WH;
    int mm = valid ? m : WH - 1;
    int yy = mm / 41, xx = mm - yy * 41;
    const float* xb = xup + (long)b * CIN * WH;

    int   off[9];
    float okf[9];
#pragma unroll
    for (int t = 0; t < 9; ++t) {
        int dy = (t / 3) * 6 - 6, dx = (t % 3) * 6 - 6;
        int y = yy + dy, xc = xx + dx;
        bool ok = (y >= 0 && y < 41 && xc >= 0 && xc < 41);
        okf[t] = ok ? 1.f : 0.f;
        off[t] = (ok ? y : yy) * 41 + (ok ? xc : xx);   // safe addr
    }
    float acc[6] = {0, 0, 0, 0, 0, 0};
    for (int i = i0; i < i0 + 256; ++i) {
        const float* xr = xb + (long)i * WH;
        float xv[9];
#pragma unroll
        for (int t = 0; t < 9; ++t) xv[t] = okf[t] * xr[off[t]];
        const float* wr = w2 + (long)i * 288 + cg * 12;
#pragma unroll
        for (int j = 0; j < 6; ++j) {
            const float4 wa = *(const float4*)(wr + j * 48);
            const float4 wb = *(const float4*)(wr + j * 48 + 4);
            float w8 = wr[j * 48 + 8];
            acc[j] += wa.x * xv[0] + wa.y * xv[1] + wa.z * xv[2] + wa.w * xv[3]
                    + wb.x * xv[4] + wb.y * xv[5] + wb.z * xv[6] + wb.w * xv[7]
                    + w8 * xv[8];
        }
    }
    if (valid) {
#pragma unroll
        for (int j = 0; j < 6; ++j) {
            int c = cg + 4 * j;
            if (c < NCLS) atomicAdd(&g[((long)b * NCLS + c) * WH + m], acc[j]);
        }
    }
}

// one pass over diffW computing all 4 scales' masked row-averages
// grid (1681, 4) x 256 : block = (m,b); wave w handles classes [6w, 6w+6) (last: 3)
__global__ void k_diffuse(const float* __restrict__ diffW, const float* __restrict__ g,
                          const float* __restrict__ msc, const float* __restrict__ Kc,
                          float* __restrict__ wcum) {
    int mrow = blockIdx.x, b = blockIdx.y;
    int lane = threadIdx.x & 63, wv = threadIdx.x >> 6;
    int c0 = wv * 6;
    int nc = (wv == 3) ? 3 : 6;
    float s0 = msc[0], s1 = msc[1], s2 = msc[2], s3 = msc[3];
    const float* dr = diffW + ((long)b * WH + mrow) * WH;
    const float* gb = g + (long)b * NCLS * WH;
    float acc[4][6];
    float cnt[4] = {0, 0, 0, 0};
#pragma unroll
    for (int it = 0; it < 4; ++it)
#pragma unroll
        for (int j = 0; j < 6; ++j) acc[it][j] = 0.f;

    for (int n = lane; n < WH; n += 64) {
        float dw = dr[n];
        float m0 = dw > s0 ? 1.f : 0.f;
        float m1 = dw > s1 ? 1.f : 0.f;
        float m2 = dw > s2 ? 1.f : 0.f;
        float m3 = dw > s3 ? 1.f : 0.f;
        cnt[0] += m0; cnt[1] += m1; cnt[2] += m2; cnt[3] += m3;
#pragma unroll
        for (int j = 0; j < 6; ++j) {
            if (j < nc) {
                float gv = gb[(c0 + j) * WH + n];
                acc[0][j] += m0 * gv;
                acc[1][j] += m1 * gv;
                acc[2][j] += m2 * gv;
                acc[3][j] += m3 * gv;
            }
        }
    }
#pragma unroll
    for (int o = 1; o < 64; o <<= 1) {
#pragma unroll
        for (int it = 0; it < 4; ++it) {
            cnt[it] += __shfl_xor(cnt[it], o, 64);
#pragma unroll
            for (int j = 0; j < 6; ++j) acc[it][j] += __shfl_xor(acc[it][j], o, 64);
        }
    }
    if (lane == 0) {
#pragma unroll
        for (int it = 0; it < 4; ++it) {
            float inv = 1.0f / cnt[it];
            for (int j = 0; j < nc; ++j) {
                int c = c0 + j;
                wcum[(((long)b * 4 + it) * NCLS + c) * WH + mrow] = acc[it][j] * inv + Kc[c];
            }
        }
    }
}

// per-(b,m): scale-softmax mask, fused logits, two 21-way softmaxes.
// writes wei_mask, wei_cum2, wei outputs. grid 27 x 256
__global__ void k_mask(const float* __restrict__ wcum, const float* __restrict__ smw,
                       float* __restrict__ out_wc2, float* __restrict__ out_wei,
                       float* __restrict__ out_mask) {
    int gid = blockIdx.x * blockDim.x + threadIdx.x;
    if (gid >= BS * WH) return;
    int b = gid / WH, m = gid - b * WH;
    const float* base = wcum + (long)b * 4 * NCLS * WH + m;

    float fused[21];
#pragma unroll
    for (int c = 0; c < NCLS; ++c) {
        float sc = smw[c];
        float L0 = base[(0 * NCLS + c) * WH];
        float L1 = base[(1 * NCLS + c) * WH];
        float L2 = base[(2 * NCLS + c) * WH];
        float L3 = base[(3 * NCLS + c) * WH];
        float a0 = sc * L0, a1 = sc * L1, a2 = sc * L2, a3 = sc * L3;
        float mx = fmaxf(fmaxf(a0, a1), fmaxf(a2, a3));
        float e0 = __expf(a0 - mx), e1 = __expf(a1 - mx), e2 = __expf(a2 - mx), e3 = __expf(a3 - mx);
        float inv = 1.0f / (e0 + e1 + e2 + e3);
        e0 *= inv; e1 *= inv; e2 *= inv; e3 *= inv;
        out_mask[((long)(b * 4 + 0) * NCLS + c) * WH + m] = e0;
        out_mask[((long)(b * 4 + 1) * NCLS + c) * WH + m] = e1;
        out_mask[((long)(b * 4 + 2) * NCLS + c) * WH + m] = e2;
        out_mask[((long)(b * 4 + 3) * NCLS + c) * WH + m] = e3;
        fused[c] = L0 * e0 + L1 * e1 + L2 * e2 + L3 * e3;
    }
    // softmax over classes -> wei_cum2
    float mx = -1e30f;
#pragma unroll
    for (int c = 0; c < NCLS; ++c) mx = fmaxf(mx, fused[c]);
    float s = 0.f;
    float e[21];
#pragma unroll
    for (int c = 0; c < NCLS; ++c) { e[c] = __expf(fused[c] - mx); s += e[c]; }
    float inv = 1.0f / s;
#pragma unroll
    for (int c = 0; c < NCLS; ++c) {
        e[c] *= inv;
        out_wc2[((long)b * NCLS + c) * WH + m] = e[c];
    }
    // softmax again -> wei
    mx = -1e30f;
#pragma unroll
    for (int c = 0; c < NCLS; ++c) mx = fmaxf(mx, e[c]);
    s = 0.f;
    float e2a[21];
#pragma unroll
    for (int c = 0; c < NCLS; ++c) { e2a[c] = __expf(e[c] - mx); s += e2a[c]; }
    inv = 1.0f / s;
#pragma unroll
    for (int c = 0; c < NCLS; ++c) out_wei[((long)b * NCLS + c) * WH + m] = e2a[c] * inv;
}

// per-(b,c): softmax-pool over m with g, sigmoid. grid (21,4) x 256
__global__ void k_pool(const float* __restrict__ wei, const float* __restrict__ g,
                       const float* __restrict__ poolw, const float* __restrict__ Kc,
                       float* __restrict__ prob) {
    int c = blockIdx.x, b = blockIdx.y;
    const float* wr = wei + ((long)b * NCLS + c) * WH;
    const float* gr = g + ((long)b * NCLS + c) * WH;
    float E = __expf(poolw[c]);
    __shared__ float red[256];
    float mx = -1e30f;
    for (int m = threadIdx.x; m < WH; m += 256) mx = fmaxf(mx, wr[m] * E);
    red[threadIdx.x] = mx; __syncthreads();
    for (int o = 128; o > 0; o >>= 1) {
        if (threadIdx.x < o) red[threadIdx.x] = fmaxf(red[threadIdx.x], red[threadIdx.x + o]);
        __syncthreads();
    }
    mx = red[0]; __syncthreads();
    float se = 0.f, sg = 0.f;
    for (int m = threadIdx.x; m < WH; m += 256) {
        float ev = __expf(wr[m] * E - mx);
        se += ev; sg += ev * gr[m];
    }
    red[threadIdx.x] = se; __syncthreads();
    for (int o = 128; o > 0; o >>= 1) {
        if (threadIdx.x < o) red[threadIdx.x] += red[threadIdx.x + o];
        __syncthreads();
    }
    se = red[0]; __syncthreads();
    red[threadIdx.x] = sg; __syncthreads();
    for (int o = 128; o > 0; o >>= 1) {
        if (threadIdx.x < o) red[threadIdx.x] += red[threadIdx.x + o];
        __syncthreads();
    }
    sg = red[0];
    if (threadIdx.x == 0) {
        float out = sg / se + Kc[c];
        prob[b * NCLS + c] = 1.0f / (1.0f + __expf(-out));
    }
}

// ---------------- launcher ----------------
extern "C" void kernel_launch(void* const* d_in, const int* in_sizes, int n_in,
                              void* d_out, int out_size, void* d_ws, size_t ws_size,
                              hipStream_t stream) {
    const float* x      = (const float*)d_in[0];
    const float* diffW  = (const float*)d_in[1];
    const float* conv_w = (const float*)d_in[2];
    const float* conv_b = (const float*)d_in[3];
    const float* cls_w  = (const float*)d_in[4];
    const float* cls_b  = (const float*)d_in[5];
    const float* smw    = (const float*)d_in[6];
    const float* poolw  = (const float*)d_in[7];
    const float* msc    = (const float*)d_in[8];

    float* ws   = (float*)d_ws;
    float* xup  = ws + WS_XUP;
    float* w2   = ws + WS_W2;
    float* g    = ws + WS_G;
    float* Kc   = ws + WS_KC;
    float* wcum = ws + WS_WCUM;

    float* out  = (float*)d_out;
    float* o_prob = out;                 // [4][1][21]
    float* o_wc2  = out + 84;            // [4][21][1681]
    float* o_wei  = out + 84 + 84021 * 0 + 141204;   // 84 + 141204
    float* o_mask = out + 84 + 141204 + 141204;

    hipMemsetAsync(g, 0, 141204 * sizeof(float), stream);
    hipMemsetAsync(w2, 0, 589824 * sizeof(float), stream);

    {
        int total = BS * CIN * WH;
        int blocks = (total + 255) / 256;
        k_upsample<<<blocks, 256, 0, stream>>>(x, xup, total);
    }
    k_merge<<<dim3(KPOS / 64, 2), 256, 0, stream>>>(conv_w, cls_w, w2);
    k_const<<<NCLS, 256, 0, stream>>>(cls_w, conv_b, cls_b, Kc);
    k_conv<<<dim3(27, BS, 8), 256, 0, stream>>>(xup, w2, g);
    k_diffuse<<<dim3(WH, BS), 256, 0, stream>>>(diffW, g, msc, Kc, wcum);
    k_mask<<<(BS * WH + 255) / 256, 256, 0, stream>>>(wcum, smw, o_wc2, o_wei, o_mask);
    k_pool<<<dim3(NCLS, BS), 256, 0, stream>>>(o_wei, g, poolw, Kc, o_prob);
}

// Round 2
// 336.241 us; speedup vs baseline: 2.7104x; 2.7104x over previous
//
#include <hip/hip_runtime.h>
#include <hip/hip_bf16.h>
#include <math.h>

#define NCLS 21
#define WH 1681          // 41*41
#define BS 4
#define CIN 2048
#define NSRC 1089        // 33*33
#define KPOS 18432       // 2048*9
#define MR 192           // 21*9=189 padded to 192
#define HS 836352        // 4*192*1089 : one k-split slab of H2

// ---------------- ws layout (floats) ----------------
// w2m  : [192][2048]          393,216
// Kc   : [32]
// H2   : [2][4][192][1089]  1,672,704
// wcum : [4][4][21][1681]     564,816
// g    : [4][21][1681]        141,204
#define WS_W2M  0L
#define WS_KC   393216L
#define WS_H2   (WS_KC + 32L)
#define WS_WCUM (WS_H2 + 2L * HS)
#define WS_G    (WS_WCUM + 564816L)

// ---------------- kernels ----------------

// w2m[c*9+t][i] = sum_d cls_w[c,d] * conv_w[d, i, t]
// grid (288, 4) x 256; d-split 4 via atomicAdd (w2m pre-zeroed)
__global__ void k_merge(const float* __restrict__ convw, const float* __restrict__ clsw,
                        float* __restrict__ w2m) {
    int pos = blockIdx.x * 64 + (threadIdx.x & 63);
    int cg  = threadIdx.x >> 6;            // 0..3
    int d0  = blockIdx.y * 256;
    float acc[6] = {0, 0, 0, 0, 0, 0};
    for (int d = d0; d < d0 + 256; d += 4) {
        float c0 = convw[(long)(d + 0) * KPOS + pos];
        float c1 = convw[(long)(d + 1) * KPOS + pos];
        float c2 = convw[(long)(d + 2) * KPOS + pos];
        float c3 = convw[(long)(d + 3) * KPOS + pos];
#pragma unroll
        for (int j = 0; j < 6; ++j) {
            int c = cg + 4 * j;
            if (c < NCLS) {
                const float4 w = *(const float4*)&clsw[c * 1024 + d];
                acc[j] += w.x * c0 + w.y * c1 + w.z * c2 + w.w * c3;
            }
        }
    }
    int i = pos / 9, t = pos - i * 9;
#pragma unroll
    for (int j = 0; j < 6; ++j) {
        int c = cg + 4 * j;
        if (c < NCLS) atomicAdd(&w2m[(long)(c * 9 + t) * 2048 + i], acc[j]);
    }
}

// Kc[c] = sum_d cls_w[c,d]*conv_b[d] + cls_b[c] ; grid 21 x 256
__global__ void k_const(const float* __restrict__ clsw, const float* __restrict__ convb,
                        const float* __restrict__ clsb, float* __restrict__ Kc) {
    __shared__ float red[256];
    int c = blockIdx.x;
    float s = 0.f;
    for (int d = threadIdx.x; d < 1024; d += 256) s += clsw[c * 1024 + d] * convb[d];
    red[threadIdx.x] = s; __syncthreads();
    for (int o = 128; o > 0; o >>= 1) {
        if (threadIdx.x < o) red[threadIdx.x] += red[threadIdx.x + o];
        __syncthreads();
    }
    if (threadIdx.x == 0) Kc[c] = red[0] + clsb[c];
}

// H2[ks][b][r][n] = sum_{k in split ks} w2m[r][k] * x[b][k][n]
// grid (18 ntile, 3 mtile, 8 = b*2+ks) x 256; 64x64 tile, KC=32, reg-prefetch
__global__ __launch_bounds__(256) void k_gemm(const float* __restrict__ w2m,
                                              const float* __restrict__ x,
                                              float* __restrict__ H2) {
    __shared__ float As[32][68];   // padded: transpose-store, 16B-aligned rows
    __shared__ float Bs[32][64];
    int tid = threadIdx.x;
    int n0 = blockIdx.x * 64;
    int m0 = blockIdx.y * 64;
    int b  = blockIdx.z >> 1;
    int ks = blockIdx.z & 1;
    int k0 = ks * 1024;

    int la_m = tid >> 5;           // 0..7
    int la_k = tid & 31;
    int lb_n = tid & 63;
    int lb_k = tid >> 6;           // 0..3
    int tn = tid & 15, tm = tid >> 4;

    const float* Ab = w2m + (long)m0 * 2048 + k0;
    const float* Bb = x + ((long)b * CIN + k0) * NSRC + n0 + lb_n;
    bool bok = (n0 + lb_n) < NSRC;

    float ra[8], rb[8];
#pragma unroll
    for (int j = 0; j < 8; ++j) ra[j] = Ab[(la_m + 8 * j) * 2048 + la_k];
#pragma unroll
    for (int j = 0; j < 8; ++j) rb[j] = bok ? Bb[(long)(lb_k + 4 * j) * NSRC] : 0.f;

    float acc[4][4];
#pragma unroll
    for (int i_ = 0; i_ < 4; ++i_)
#pragma unroll
        for (int j_ = 0; j_ < 4; ++j_) acc[i_][j_] = 0.f;

    for (int kt = 0; kt < 32; ++kt) {
#pragma unroll
        for (int j = 0; j < 8; ++j) As[la_k][la_m + 8 * j] = ra[j];
#pragma unroll
        for (int j = 0; j < 8; ++j) Bs[lb_k + 4 * j][lb_n] = rb[j];
        __syncthreads();
        if (kt < 31) {
            const float* An = Ab + (kt + 1) * 32;
            const float* Bn = Bb + (long)(kt + 1) * 32 * NSRC;
#pragma unroll
            for (int j = 0; j < 8; ++j) ra[j] = An[(la_m + 8 * j) * 2048 + la_k];
#pragma unroll
            for (int j = 0; j < 8; ++j) rb[j] = bok ? Bn[(long)(lb_k + 4 * j) * NSRC] : 0.f;
        }
#pragma unroll
        for (int kk = 0; kk < 32; ++kk) {
            float4 a4 = *(const float4*)&As[kk][tm * 4];
            float4 b4 = *(const float4*)&Bs[kk][tn * 4];
            acc[0][0] += a4.x * b4.x; acc[0][1] += a4.x * b4.y; acc[0][2] += a4.x * b4.z; acc[0][3] += a4.x * b4.w;
            acc[1][0] += a4.y * b4.x; acc[1][1] += a4.y * b4.y; acc[1][2] += a4.y * b4.z; acc[1][3] += a4.y * b4.w;
            acc[2][0] += a4.z * b4.x; acc[2][1] += a4.z * b4.y; acc[2][2] += a4.z * b4.z; acc[2][3] += a4.z * b4.w;
            acc[3][0] += a4.w * b4.x; acc[3][1] += a4.w * b4.y; acc[3][2] += a4.w * b4.z; acc[3][3] += a4.w * b4.w;
        }
        __syncthreads();
    }
    float* Hb = H2 + ((long)(ks * 4 + b) * MR + m0 + tm * 4) * NSRC + n0 + tn * 4;
#pragma unroll
    for (int ri = 0; ri < 4; ++ri)
#pragma unroll
        for (int rj = 0; rj < 4; ++rj)
            if (n0 + tn * 4 + rj < NSRC) Hb[(long)ri * NSRC + rj] = acc[ri][rj];
}

// g[b][c][m] = sum_t ok(m,t) * Bilinear41->33(H[b][c*9+t], m shifted by tap t)
// grid 552 x 256, thread = (b,c,m)
__global__ void k_combine(const float* __restrict__ H2, float* __restrict__ g) {
    int gid = blockIdx.x * blockDim.x + threadIdx.x;
    if (gid >= BS * NCLS * WH) return;
    int m = gid % WH;
    int t_ = gid / WH;
    int c = t_ % NCLS;
    int b = t_ / NCLS;
    int yy = m / 41, xx = m - yy * 41;
    const float S = 33.0f / 41.0f;
    int y0a[3], y1a[3], x0a[3], x1a[3];
    float wya[3], wxa[3];
    bool oky[3], okx[3];
#pragma unroll
    for (int o = 0; o < 3; ++o) {
        int yp = yy + 6 * o - 6;
        oky[o] = (yp >= 0 && yp < 41);
        float sy = (yp + 0.5f) * S - 0.5f;
        float fy = floorf(sy);
        wya[o] = sy - fy;
        int y0 = (int)fy;
        y0a[o] = min(max(y0, 0), 32);
        y1a[o] = min(max(y0 + 1, 0), 32);
        int xp = xx + 6 * o - 6;
        okx[o] = (xp >= 0 && xp < 41);
        float sx = (xp + 0.5f) * S - 0.5f;
        float fx = floorf(sx);
        wxa[o] = sx - fx;
        int x0 = (int)fx;
        x0a[o] = min(max(x0, 0), 32);
        x1a[o] = min(max(x0 + 1, 0), 32);
    }
    float acc = 0.f;
    const float* Hb = H2 + ((long)b * MR + c * 9) * NSRC;
#pragma unroll
    for (int ty = 0; ty < 3; ++ty) {
#pragma unroll
        for (int tx = 0; tx < 3; ++tx) {
            if (oky[ty] && okx[tx]) {
                const float* hr = Hb + (ty * 3 + tx) * NSRC;
                int i00 = y0a[ty] * 33 + x0a[tx], i01 = y0a[ty] * 33 + x1a[tx];
                int i10 = y1a[ty] * 33 + x0a[tx], i11 = y1a[ty] * 33 + x1a[tx];
                float v00 = hr[i00] + hr[i00 + HS];
                float v01 = hr[i01] + hr[i01 + HS];
                float v10 = hr[i10] + hr[i10 + HS];
                float v11 = hr[i11] + hr[i11 + HS];
                float wy = wya[ty], wx = wxa[tx];
                float v0 = v00 + wx * (v01 - v00);
                float v1 = v10 + wx * (v11 - v10);
                acc += v0 + wy * (v1 - v0);
            }
        }
    }
    g[gid] = acc;
}

// one pass over diffW computing all 4 scales' masked row-averages
// grid (1681, 4) x 256 : block = (m,b); wave w handles classes [6w, 6w+6) (last: 3)
__global__ void k_diffuse(const float* __restrict__ diffW, const float* __restrict__ g,
                          const float* __restrict__ msc, const float* __restrict__ Kc,
                          float* __restrict__ wcum) {
    int mrow = blockIdx.x, b = blockIdx.y;
    int lane = threadIdx.x & 63, wv = threadIdx.x >> 6;
    int c0 = wv * 6;
    int nc = (wv == 3) ? 3 : 6;
    float s0 = msc[0], s1 = msc[1], s2 = msc[2], s3 = msc[3];
    const float* dr = diffW + ((long)b * WH + mrow) * WH;
    const float* gb = g + (long)b * NCLS * WH;
    float acc[4][6];
    float cnt[4] = {0, 0, 0, 0};
#pragma unroll
    for (int it = 0; it < 4; ++it)
#pragma unroll
        for (int j = 0; j < 6; ++j) acc[it][j] = 0.f;

    for (int n = lane; n < WH; n += 64) {
        float dw = dr[n];
        float m0 = dw > s0 ? 1.f : 0.f;
        float m1 = dw > s1 ? 1.f : 0.f;
        float m2 = dw > s2 ? 1.f : 0.f;
        float m3 = dw > s3 ? 1.f : 0.f;
        cnt[0] += m0; cnt[1] += m1; cnt[2] += m2; cnt[3] += m3;
#pragma unroll
        for (int j = 0; j < 6; ++j) {
            if (j < nc) {
                float gv = gb[(c0 + j) * WH + n];
                acc[0][j] += m0 * gv;
                acc[1][j] += m1 * gv;
                acc[2][j] += m2 * gv;
                acc[3][j] += m3 * gv;
            }
        }
    }
#pragma unroll
    for (int o = 1; o < 64; o <<= 1) {
#pragma unroll
        for (int it = 0; it < 4; ++it) {
            cnt[it] += __shfl_xor(cnt[it], o, 64);
#pragma unroll
            for (int j = 0; j < 6; ++j) acc[it][j] += __shfl_xor(acc[it][j], o, 64);
        }
    }
    if (lane == 0) {
#pragma unroll
        for (int it = 0; it < 4; ++it) {
            float inv = 1.0f / cnt[it];
            for (int j = 0; j < nc; ++j) {
                int c = c0 + j;
                wcum[(((long)b * 4 + it) * NCLS + c) * WH + mrow] = acc[it][j] * inv + Kc[c];
            }
        }
    }
}

// per-(b,m): scale-softmax mask, fused logits, two 21-way softmaxes.
__global__ void k_mask(const float* __restrict__ wcum, const float* __restrict__ smw,
                       float* __restrict__ out_wc2, float* __restrict__ out_wei,
                       float* __restrict__ out_mask) {
    int gid = blockIdx.x * blockDim.x + threadIdx.x;
    if (gid >= BS * WH) return;
    int b = gid / WH, m = gid - b * WH;
    const float* base = wcum + (long)b * 4 * NCLS * WH + m;

    float fused[21];
#pragma unroll
    for (int c = 0; c < NCLS; ++c) {
        float sc = smw[c];
        float L0 = base[(0 * NCLS + c) * WH];
        float L1 = base[(1 * NCLS + c) * WH];
        float L2 = base[(2 * NCLS + c) * WH];
        float L3 = base[(3 * NCLS + c) * WH];
        float a0 = sc * L0, a1 = sc * L1, a2 = sc * L2, a3 = sc * L3;
        float mx = fmaxf(fmaxf(a0, a1), fmaxf(a2, a3));
        float e0 = __expf(a0 - mx), e1 = __expf(a1 - mx), e2 = __expf(a2 - mx), e3 = __expf(a3 - mx);
        float inv = 1.0f / (e0 + e1 + e2 + e3);
        e0 *= inv; e1 *= inv; e2 *= inv; e3 *= inv;
        out_mask[((long)(b * 4 + 0) * NCLS + c) * WH + m] = e0;
        out_mask[((long)(b * 4 + 1) * NCLS + c) * WH + m] = e1;
        out_mask[((long)(b * 4 + 2) * NCLS + c) * WH + m] = e2;
        out_mask[((long)(b * 4 + 3) * NCLS + c) * WH + m] = e3;
        fused[c] = L0 * e0 + L1 * e1 + L2 * e2 + L3 * e3;
    }
    float mx = -1e30f;
#pragma unroll
    for (int c = 0; c < NCLS; ++c) mx = fmaxf(mx, fused[c]);
    float s = 0.f;
    float e[21];
#pragma unroll
    for (int c = 0; c < NCLS; ++c) { e[c] = __expf(fused[c] - mx); s += e[c]; }
    float inv = 1.0f / s;
#pragma unroll
    for (int c = 0; c < NCLS; ++c) {
        e[c] *= inv;
        out_wc2[((long)b * NCLS + c) * WH + m] = e[c];
    }
    mx = -1e30f;
#pragma unroll
    for (int c = 0; c < NCLS; ++c) mx = fmaxf(mx, e[c]);
    s = 0.f;
    float e2a[21];
#pragma unroll
    for (int c = 0; c < NCLS; ++c) { e2a[c] = __expf(e[c] - mx); s += e2a[c]; }
    inv = 1.0f / s;
#pragma unroll
    for (int c = 0; c < NCLS; ++c) out_wei[((long)b * NCLS + c) * WH + m] = e2a[c] * inv;
}

// per-(b,c): softmax-pool over m with g, sigmoid. grid (21,4) x 256
__global__ void k_pool(const float* __restrict__ wei, const float* __restrict__ g,
                       const float* __restrict__ poolw, const float* __restrict__ Kc,
                       float* __restrict__ prob) {
    int c = blockIdx.x, b = blockIdx.y;
    const float* wr = wei + ((long)b * NCLS + c) * WH;
    const float* gr = g + ((long)b * NCLS + c) * WH;
    float E = __expf(poolw[c]);
    __shared__ float red[256];
    float mx = -1e30f;
    for (int m = threadIdx.x; m < WH; m += 256) mx = fmaxf(mx, wr[m] * E);
    red[threadIdx.x] = mx; __syncthreads();
    for (int o = 128; o > 0; o >>= 1) {
        if (threadIdx.x < o) red[threadIdx.x] = fmaxf(red[threadIdx.x], red[threadIdx.x + o]);
        __syncthreads();
    }
    mx = red[0]; __syncthreads();
    float se = 0.f, sg = 0.f;
    for (int m = threadIdx.x; m < WH; m += 256) {
        float ev = __expf(wr[m] * E - mx);
        se += ev; sg += ev * gr[m];
    }
    red[threadIdx.x] = se; __syncthreads();
    for (int o = 128; o > 0; o >>= 1) {
        if (threadIdx.x < o) red[threadIdx.x] += red[threadIdx.x + o];
        __syncthreads();
    }
    se = red[0]; __syncthreads();
    red[threadIdx.x] = sg; __syncthreads();
    for (int o = 128; o > 0; o >>= 1) {
        if (threadIdx.x < o) red[threadIdx.x] += red[threadIdx.x + o];
        __syncthreads();
    }
    sg = red[0];
    if (threadIdx.x == 0) {
        float out = sg / se + Kc[c];
        prob[b * NCLS + c] = 1.0f / (1.0f + __expf(-out));
    }
}

// ---------------- launcher ----------------
extern "C" void kernel_launch(void* const* d_in, const int* in_sizes, int n_in,
                              void* d_out, int out_size, void* d_ws, size_t ws_size,
                              hipStream_t stream) {
    const float* x      = (const float*)d_in[0];
    const float* diffW  = (const float*)d_in[1];
    const float* conv_w = (const float*)d_in[2];
    const float* conv_b = (const float*)d_in[3];
    const float* cls_w  = (const float*)d_in[4];
    const float* cls_b  = (const float*)d_in[5];
    const float* smw    = (const float*)d_in[6];
    const float* poolw  = (const float*)d_in[7];
    const float* msc    = (const float*)d_in[8];

    float* ws   = (float*)d_ws;
    float* w2m  = ws + WS_W2M;
    float* Kc   = ws + WS_KC;
    float* H2   = ws + WS_H2;
    float* wcum = ws + WS_WCUM;
    float* g    = ws + WS_G;

    float* out  = (float*)d_out;
    float* o_prob = out;                       // [4][1][21]
    float* o_wc2  = out + 84;                  // [4][21][1681]
    float* o_wei  = out + 84 + 141204;         // [4][21][1681]
    float* o_mask = out + 84 + 141204 + 141204;// [4][4][21][1681]

    hipMemsetAsync(w2m, 0, 393216 * sizeof(float), stream);

    k_merge<<<dim3(KPOS / 64, 4), 256, 0, stream>>>(conv_w, cls_w, w2m);
    k_const<<<NCLS, 256, 0, stream>>>(cls_w, conv_b, cls_b, Kc);
    k_gemm<<<dim3(18, 3, 8), 256, 0, stream>>>(w2m, x, H2);
    k_combine<<<(BS * NCLS * WH + 255) / 256, 256, 0, stream>>>(H2, g);
    k_diffuse<<<dim3(WH, BS), 256, 0, stream>>>(diffW, g, msc, Kc, wcum);
    k_mask<<<(BS * WH + 255) / 256, 256, 0, stream>>>(wcum, smw, o_wc2, o_wei, o_mask);
    k_pool<<<dim3(NCLS, BS), 256, 0, stream>>>(o_wei, g, poolw, Kc, o_prob);
}